// Round 3
// baseline (920.072 us; speedup 1.0000x reference)
//
#include <hip/hip_runtime.h>
#include <cstdint>

#define N_NODES 100000
#define N_EDGES_C 250000
#define LATENT 128
#define N_FEAT 16
#define OUT_DIM 128
#define D_IN 272      // 16 + 128 + 128
#define KC1 9         // layer-1 K chunks of 32 (K padded 272 -> 288)
#define KC2 8
#define NT1 16        // 256 cols / 16
#define NT2 16
#define NT3 8         // 128 cols / 16
#define EPB 32        // edges per block
#define MT 2          // row-tiles per block (EPB/16)

// swizzled weight sizes in u16 elements
#define SZ1 (KC1*NT1*512)     // 73728
#define SZ2 (KC2*NT2*512)     // 65536
#define SZ3 (KC2*NT3*512)     // 32768
#define SZ_MLP (SZ1+SZ2+SZ3)  // 172032
#define SZ_ALL (2*SZ_MLP)     // 344064

typedef _Float16 f16;
typedef _Float16 f16x8 __attribute__((ext_vector_type(8)));
typedef float f32x4 __attribute__((ext_vector_type(4)));
typedef unsigned short u16;
typedef u16 u16x8 __attribute__((ext_vector_type(8)));

static __device__ __forceinline__ u16 f16_bits(float v) {
    f16 h = (f16)v;
    return __builtin_bit_cast(u16, h);
}

// ---------------------------------------------------------------------------
// Weight swizzle prep (f16): layout = [c][t][quad][n''][j] so a wave's
// B-fragment load is lane*16B contiguous (global_load_dwordx4).
// ---------------------------------------------------------------------------
__global__ void prep_weights(const float* __restrict__ W1a, const float* __restrict__ W2a,
                             const float* __restrict__ W3a, const float* __restrict__ W1b,
                             const float* __restrict__ W2b, const float* __restrict__ W3b,
                             u16* __restrict__ Whi) {
    int idx = blockIdx.x * 256 + threadIdx.x;      // grid is exactly SZ_ALL/256
    int mlp = idx / SZ_MLP;
    int r = idx - mlp * SZ_MLP;
    const float* Wsrc; int NT, Kreal, N, rl;
    if (r < SZ1)            { Wsrc = mlp ? W1b : W1a; NT = NT1; Kreal = D_IN; N = 256; rl = r; }
    else if (r < SZ1 + SZ2) { Wsrc = mlp ? W2b : W2a; NT = NT2; Kreal = 256;  N = 256; rl = r - SZ1; }
    else                    { Wsrc = mlp ? W3b : W3a; NT = NT3; Kreal = 256;  N = 128; rl = r - SZ1 - SZ2; }
    int block  = rl >> 9;
    int within = rl & 511;
    int quad = within >> 7;
    int nn   = (within >> 3) & 15;
    int j    = within & 7;
    int c = block / NT;
    int t = block - c * NT;
    int k = c * 32 + quad * 8 + j;
    int n = t * 16 + nn;
    float w = (k < Kreal) ? Wsrc[(size_t)k * N + n] : 0.f;
    Whi[idx] = f16_bits(w);
}

// ---------------------------------------------------------------------------
// Gather X = concat(ef[16], coords[p1][128], coords[p2][128]) for 32 edges,
// f16, into A-fragment-linear LDS: idx = (mt*KC1+chunk)*512 + quad*128 +
// mr*8 + j  (k = chunk*32+quad*8+j). 8 threads per edge, 36 floats each.
// ---------------------------------------------------------------------------
static __device__ __forceinline__ void gatherX(u16* __restrict__ A,
                                               const float* __restrict__ coords,
                                               const float* __restrict__ efeat,
                                               const int* __restrict__ pA,
                                               const int* __restrict__ pB,
                                               int ebase, int tid) {
    int m = tid >> 3;           // edge slot 0..31
    int p = tid & 7;
    int e = ebase + m;
    bool v = e < N_EDGES_C;
    int i1 = pA[m];
    int i2 = pB[m];
    const float* ef = efeat + (size_t)e * N_FEAT;
    const float* c1 = coords + (size_t)i1 * LATENT;
    const float* c2 = coords + (size_t)i2 * LATENT;
    int mt = m >> 4, mr = m & 15;
    int k0 = p * 36;
    #pragma unroll
    for (int kk = 0; kk < 36; kk += 4) {
        int k = k0 + kk;
        float4 val;
        if (!v || k >= D_IN)  val = make_float4(0.f, 0.f, 0.f, 0.f);
        else if (k < 16)      val = *(const float4*)(ef + k);
        else if (k < 144)     val = *(const float4*)(c1 + (k - 16));
        else                  val = *(const float4*)(c2 + (k - 144));
        int chunk = k >> 5, quad = (k >> 3) & 3, j = k & 7;
        ushort4 h;
        h.x = f16_bits(val.x); h.y = f16_bits(val.y);
        h.z = f16_bits(val.z); h.w = f16_bits(val.w);
        *(ushort4*)&A[(mt * KC1 + chunk) * 512 + quad * 128 + mr * 8 + j] = h;
    }
}

// ---------------------------------------------------------------------------
// K-loop: acc[mt][t] += A(32xK) @ W(KxN). Wave owns col-tiles
// [wave*CT, wave*CT+CT); each B frag feeds MT MFMAs. No manual prefetch
// (register budget 85) — compiler pipelines within the chunk.
// ---------------------------------------------------------------------------
template<int KCL, int CT, int NTT>
static __device__ __forceinline__ void kloop(const u16* __restrict__ A,
                                             const u16* __restrict__ W,
                                             int wave, int lane,
                                             f32x4 (&acc)[MT][CT]) {
    const int la8 = lane * 8;
    const int tg0 = wave * CT;
    #pragma unroll
    for (int c = 0; c < KCL; ++c) {
        f16x8 a[MT];
        #pragma unroll
        for (int mt = 0; mt < MT; ++mt)
            a[mt] = __builtin_bit_cast(f16x8, *(const u16x8*)&A[(mt * KC1 + c) * 512 + la8]);
        #pragma unroll
        for (int t = 0; t < CT; ++t) {
            f16x8 b = __builtin_bit_cast(f16x8, *(const u16x8*)&W[(c * NTT + tg0 + t) * 512 + la8]);
            #pragma unroll
            for (int mt = 0; mt < MT; ++mt)
                acc[mt][t] = __builtin_amdgcn_mfma_f32_16x16x32_f16(a[mt], b, acc[mt][t], 0, 0, 0);
        }
    }
}

template<int KCL, int CT, int NTT>
static __device__ __forceinline__ void layer_mm(const u16* __restrict__ A,
                                                const u16* __restrict__ W,
                                                int wave, int lane,
                                                f32x4 (&acc)[MT][CT]) {
    #pragma unroll
    for (int mt = 0; mt < MT; ++mt)
        #pragma unroll
        for (int t = 0; t < CT; ++t)
            acc[mt][t] = (f32x4){0.f, 0.f, 0.f, 0.f};
    kloop<KCL, CT, NTT>(A, W, wave, lane, acc);
}

// bias + relu + f16 -> write H back into LDS in A-fragment layout (k = n).
template<int CT>
static __device__ __forceinline__ void epi_relu(u16* __restrict__ A,
                                                const float* __restrict__ bias,
                                                int wave, int lane,
                                                f32x4 (&acc)[MT][CT]) {
    int quad = lane >> 4, ln = lane & 15;
    #pragma unroll
    for (int t = 0; t < CT; ++t) {
        int n = (wave * CT + t) * 16 + ln;
        float b = bias[n];
        int chunk = n >> 5, q2 = (n >> 3) & 3, j = n & 7;
        #pragma unroll
        for (int mt = 0; mt < MT; ++mt)
            #pragma unroll
            for (int r = 0; r < 4; ++r) {
                float v = acc[mt][t][r] + b;
                v = fmaxf(v, 0.f);
                A[(mt * KC1 + chunk) * 512 + q2 * 128 + (quad * 4 + r) * 8 + j] = f16_bits(v);
            }
    }
}

__global__ void __launch_bounds__(256, 6)
fused_mlp(const float* __restrict__ coords, const float* __restrict__ efeat,
          const float* __restrict__ nfict,
          const int* __restrict__ port1, const int* __restrict__ port2,
          const float* __restrict__ b1a, const float* __restrict__ b2a, const float* __restrict__ b3a,
          const float* __restrict__ b1b, const float* __restrict__ b2b, const float* __restrict__ b3b,
          const u16* __restrict__ Whi,
          float* __restrict__ out) {
    __shared__ u16 A[MT * KC1 * 512];   // 18432 B: X / H overlay
    __shared__ int pA[EPB], pB[EPB];
    __shared__ float mk[EPB];

    const int tid = threadIdx.x;
    const int lane = tid & 63;
    const int wave = tid >> 6;
    const int ebase = blockIdx.x * EPB;

    if (tid < EPB) {
        int e = ebase + tid;
        bool v = e < N_EDGES_C;
        pA[tid] = v ? port1[e] : 0;
        pB[tid] = v ? port2[e] : 0;
        mk[tid] = v ? nfict[e] : 0.f;
    }
    __syncthreads();
    gatherX(A, coords, efeat, pA, pB, ebase, tid);
    __syncthreads();

    #pragma unroll 1
    for (int mlp = 0; mlp < 2; ++mlp) {
        if (mlp) {                      // H2 overwrote X; re-gather (L2/L3-hot)
            __syncthreads();
            gatherX(A, coords, efeat, pA, pB, ebase, tid);
            __syncthreads();
        }
        const u16* wh = Whi + mlp * SZ_MLP;
        const float* bb1 = mlp ? b1b : b1a;
        const float* bb2 = mlp ? b2b : b2a;
        const float* bb3 = mlp ? b3b : b3a;
        const int*   pp  = mlp ? pB  : pA;

        f32x4 acc[MT][4];
        layer_mm<KC1, 4, NT1>(A, wh, wave, lane, acc);             // 272->256
        __syncthreads();
        epi_relu<4>(A, bb1, wave, lane, acc);
        __syncthreads();
        layer_mm<KC2, 4, NT2>(A, wh + SZ1, wave, lane, acc);       // 256->256
        __syncthreads();
        epi_relu<4>(A, bb2, wave, lane, acc);
        __syncthreads();
        f32x4 acc3[MT][2];
        layer_mm<KC2, 2, NT3>(A, wh + SZ1 + SZ2, wave, lane, acc3); // 256->128

        // scatter: bias, mask, atomic add into out (acc buffer, pre-zeroed)
        int quad = lane >> 4, ln = lane & 15;
        #pragma unroll
        for (int t = 0; t < 2; ++t) {
            int n = (wave * 2 + t) * 16 + ln;
            float b = bb3[n];
            #pragma unroll
            for (int mt = 0; mt < MT; ++mt)
                #pragma unroll
                for (int r = 0; r < 4; ++r) {
                    int m = mt * 16 + quad * 4 + r;
                    float v = (acc3[mt][t][r] + b) * mk[m];
                    unsafeAtomicAdd(out + (size_t)pp[m] * OUT_DIM + n, v);
                }
        }
    }
}

__global__ void tanh_kernel(float* __restrict__ out, int n) {
    int i = (blockIdx.x * 256 + threadIdx.x) * 4;
    if (i + 3 < n) {
        float4 v = *(float4*)(out + i);
        v.x = tanhf(v.x); v.y = tanhf(v.y); v.z = tanhf(v.z); v.w = tanhf(v.w);
        *(float4*)(out + i) = v;
    } else {
        for (int k = i; k < n; ++k) out[k] = tanhf(out[k]);
    }
}

extern "C" void kernel_launch(void* const* d_in, const int* in_sizes, int n_in,
                              void* d_out, int out_size, void* d_ws, size_t ws_size,
                              hipStream_t stream) {
    const float* coords = (const float*)d_in[0];
    const float* efeat  = (const float*)d_in[1];
    const float* nfict  = (const float*)d_in[2];
    const int*   p1     = (const int*)d_in[3];
    const int*   p2     = (const int*)d_in[4];
    const float* W1a = (const float*)d_in[5];  const float* b1a = (const float*)d_in[6];
    const float* W2a = (const float*)d_in[7];  const float* b2a = (const float*)d_in[8];
    const float* W3a = (const float*)d_in[9];  const float* b3a = (const float*)d_in[10];
    const float* W1b = (const float*)d_in[11]; const float* b1b = (const float*)d_in[12];
    const float* W2b = (const float*)d_in[13]; const float* b2b = (const float*)d_in[14];
    const float* W3b = (const float*)d_in[15]; const float* b3b = (const float*)d_in[16];
    float* out = (float*)d_out;
    u16* Whi = (u16*)d_ws;                 // needs SZ_ALL*2 = 688,128 B of ws

    hipMemsetAsync(d_out, 0, (size_t)out_size * sizeof(float), stream);
    prep_weights<<<SZ_ALL / 256, 256, 0, stream>>>(W1a, W2a, W3a, W1b, W2b, W3b, Whi);
    int nblk = (N_EDGES_C + EPB - 1) / EPB;
    fused_mlp<<<nblk, 256, 0, stream>>>(coords, efeat, nfict, p1, p2,
                                        b1a, b2a, b3a, b1b, b2b, b3b, Whi, out);
    int n4 = (out_size + 3) / 4;
    tanh_kernel<<<(n4 + 255) / 256, 256, 0, stream>>>(out, out_size);
}

// Round 4
// 793.185 us; speedup vs baseline: 1.1600x; 1.1600x over previous
//
#include <hip/hip_runtime.h>
#include <cstdint>

#define N_NODES 100000
#define N_EDGES_C 250000
#define LATENT 128
#define N_FEAT 16
#define OUT_DIM 128
#define D_IN 272      // 16 + 128 + 128
#define KC1 9         // layer-1 K chunks of 32 (K padded 272 -> 288)
#define KC2 8
#define NT1 16        // 256 cols / 16
#define NT2 16
#define NT3 8         // 128 cols / 16
#define EPB 32        // edges per block
#define MT 2          // row-tiles per block (EPB/16)

// swizzled weight sizes in u16 elements
#define SZ1 (KC1*NT1*512)     // 73728
#define SZ2 (KC2*NT2*512)     // 65536
#define SZ3 (KC2*NT3*512)     // 32768
#define SZ_MLP (SZ1+SZ2+SZ3)  // 172032
#define SZ_ALL (2*SZ_MLP)     // 344064

typedef _Float16 f16;
typedef _Float16 f16x8 __attribute__((ext_vector_type(8)));
typedef float f32x4 __attribute__((ext_vector_type(4)));
typedef unsigned short u16;
typedef u16 u16x8 __attribute__((ext_vector_type(8)));

static __device__ __forceinline__ u16 f16_bits(float v) {
    f16 h = (f16)v;
    return __builtin_bit_cast(u16, h);
}

// ---------------------------------------------------------------------------
// Weight swizzle prep (f16): layout = [c][t][quad][n''][j] so a wave's
// B-fragment load is lane*16B contiguous (global_load_dwordx4).
// ---------------------------------------------------------------------------
__global__ void prep_weights(const float* __restrict__ W1a, const float* __restrict__ W2a,
                             const float* __restrict__ W3a, const float* __restrict__ W1b,
                             const float* __restrict__ W2b, const float* __restrict__ W3b,
                             u16* __restrict__ Whi) {
    int idx = blockIdx.x * 256 + threadIdx.x;      // grid is exactly SZ_ALL/256
    int mlp = idx / SZ_MLP;
    int r = idx - mlp * SZ_MLP;
    const float* Wsrc; int NT, Kreal, N, rl;
    if (r < SZ1)            { Wsrc = mlp ? W1b : W1a; NT = NT1; Kreal = D_IN; N = 256; rl = r; }
    else if (r < SZ1 + SZ2) { Wsrc = mlp ? W2b : W2a; NT = NT2; Kreal = 256;  N = 256; rl = r - SZ1; }
    else                    { Wsrc = mlp ? W3b : W3a; NT = NT3; Kreal = 256;  N = 128; rl = r - SZ1 - SZ2; }
    int block  = rl >> 9;
    int within = rl & 511;
    int quad = within >> 7;
    int nn   = (within >> 3) & 15;
    int j    = within & 7;
    int c = block / NT;
    int t = block - c * NT;
    int k = c * 32 + quad * 8 + j;
    int n = t * 16 + nn;
    float w = (k < Kreal) ? Wsrc[(size_t)k * N + n] : 0.f;
    Whi[idx] = f16_bits(w);
}

// ---------------------------------------------------------------------------
// Gather X = concat(ef[16], coords[p1][128], coords[p2][128]) for 32 edges,
// f16, into A-fragment-linear LDS (stride KC1). Non-temporal loads: the
// random gather stream must not evict the L2-resident weight set.
// 8 threads per edge, 36 floats each.
// ---------------------------------------------------------------------------
static __device__ __forceinline__ void gatherX(u16* __restrict__ A,
                                               const float* __restrict__ coords,
                                               const float* __restrict__ efeat,
                                               const int* __restrict__ pA,
                                               const int* __restrict__ pB,
                                               int ebase, int tid) {
    int m = tid >> 3;           // edge slot 0..31
    int p = tid & 7;
    int e = ebase + m;
    bool v = e < N_EDGES_C;
    int i1 = pA[m];
    int i2 = pB[m];
    const float* ef = efeat + (size_t)e * N_FEAT;
    const float* c1 = coords + (size_t)i1 * LATENT;
    const float* c2 = coords + (size_t)i2 * LATENT;
    int mt = m >> 4, mr = m & 15;
    int k0 = p * 36;
    #pragma unroll
    for (int kk = 0; kk < 36; kk += 4) {
        int k = k0 + kk;
        f32x4 val;
        if (!v || k >= D_IN)  val = (f32x4){0.f, 0.f, 0.f, 0.f};
        else if (k < 16)      val = __builtin_nontemporal_load((const f32x4*)(ef + k));
        else if (k < 144)     val = __builtin_nontemporal_load((const f32x4*)(c1 + (k - 16)));
        else                  val = __builtin_nontemporal_load((const f32x4*)(c2 + (k - 144)));
        int chunk = k >> 5, quad = (k >> 3) & 3, j = k & 7;
        ushort4 h;
        h.x = f16_bits(val.x); h.y = f16_bits(val.y);
        h.z = f16_bits(val.z); h.w = f16_bits(val.w);
        *(ushort4*)&A[(mt * KC1 + chunk) * 512 + quad * 128 + mr * 8 + j] = h;
    }
}

// ---------------------------------------------------------------------------
// K-loop with one-chunk rotating prefetch of B (global/L2) and A (LDS):
// acc[mt][t] += A(32xK) @ W(KxN). Wave owns col-tiles [wave*CT, +CT).
// KCA = A-region chunk stride (KC1 for X, KC2 for H).
// ---------------------------------------------------------------------------
template<int KCL, int KCA, int CT, int NTT>
static __device__ __forceinline__ void kloop(const u16* __restrict__ A,
                                             const u16* __restrict__ W,
                                             int wave, int lane,
                                             f32x4 (&acc)[MT][CT]) {
    const int la8 = lane * 8;
    const int tg0 = wave * CT;
    u16x8 b[CT];
    f16x8 a[MT];
    #pragma unroll
    for (int t = 0; t < CT; ++t)
        b[t] = *(const u16x8*)&W[(tg0 + t) * 512 + la8];
    #pragma unroll
    for (int mt = 0; mt < MT; ++mt)
        a[mt] = __builtin_bit_cast(f16x8, *(const u16x8*)&A[(mt * KCA) * 512 + la8]);
    #pragma unroll
    for (int c = 0; c < KCL; ++c) {
        u16x8 bn[CT];
        f16x8 an[MT];
        if (c + 1 < KCL) {
            #pragma unroll
            for (int t = 0; t < CT; ++t)
                bn[t] = *(const u16x8*)&W[((c + 1) * NTT + tg0 + t) * 512 + la8];
            #pragma unroll
            for (int mt = 0; mt < MT; ++mt)
                an[mt] = __builtin_bit_cast(f16x8, *(const u16x8*)&A[(mt * KCA + c + 1) * 512 + la8]);
        }
        #pragma unroll
        for (int t = 0; t < CT; ++t) {
            f16x8 bf = __builtin_bit_cast(f16x8, b[t]);
            #pragma unroll
            for (int mt = 0; mt < MT; ++mt)
                acc[mt][t] = __builtin_amdgcn_mfma_f32_16x16x32_f16(a[mt], bf, acc[mt][t], 0, 0, 0);
        }
        if (c + 1 < KCL) {
            #pragma unroll
            for (int t = 0; t < CT; ++t) b[t] = bn[t];
            #pragma unroll
            for (int mt = 0; mt < MT; ++mt) a[mt] = an[mt];
        }
    }
}

template<int KCL, int KCA, int CT, int NTT>
static __device__ __forceinline__ void layer_mm(const u16* __restrict__ A,
                                                const u16* __restrict__ W,
                                                int wave, int lane,
                                                f32x4 (&acc)[MT][CT]) {
    #pragma unroll
    for (int mt = 0; mt < MT; ++mt)
        #pragma unroll
        for (int t = 0; t < CT; ++t)
            acc[mt][t] = (f32x4){0.f, 0.f, 0.f, 0.f};
    kloop<KCL, KCA, CT, NTT>(A, W, wave, lane, acc);
}

// bias + relu + f16 -> write H into LDS in A-fragment layout (k = n, KC2 stride).
template<int CT>
static __device__ __forceinline__ void epi_relu(u16* __restrict__ H,
                                                const float* __restrict__ bias,
                                                int wave, int lane,
                                                f32x4 (&acc)[MT][CT]) {
    int quad = lane >> 4, ln = lane & 15;
    #pragma unroll
    for (int t = 0; t < CT; ++t) {
        int n = (wave * CT + t) * 16 + ln;
        float b = bias[n];
        int chunk = n >> 5, q2 = (n >> 3) & 3, j = n & 7;
        #pragma unroll
        for (int mt = 0; mt < MT; ++mt)
            #pragma unroll
            for (int r = 0; r < 4; ++r) {
                float v = acc[mt][t][r] + b;
                v = fmaxf(v, 0.f);
                H[(mt * KC2 + chunk) * 512 + q2 * 128 + (quad * 4 + r) * 8 + j] = f16_bits(v);
            }
    }
}

__global__ void __launch_bounds__(256, 4)
fused_mlp(const float* __restrict__ coords, const float* __restrict__ efeat,
          const float* __restrict__ nfict,
          const int* __restrict__ port1, const int* __restrict__ port2,
          const float* __restrict__ b1a, const float* __restrict__ b2a, const float* __restrict__ b3a,
          const float* __restrict__ b1b, const float* __restrict__ b2b, const float* __restrict__ b3b,
          const u16* __restrict__ Whi,
          float* __restrict__ out) {
    __shared__ u16 X[MT * KC1 * 512];   // 18432 B: gathered input, persists
    __shared__ u16 H[MT * KC2 * 512];   // 16384 B: H1, overwritten by H2
    __shared__ int pA[EPB], pB[EPB];
    __shared__ float mk[EPB];

    const int tid = threadIdx.x;
    const int lane = tid & 63;
    const int wave = tid >> 6;
    const int ebase = blockIdx.x * EPB;

    if (tid < EPB) {
        int e = ebase + tid;
        bool v = e < N_EDGES_C;
        pA[tid] = v ? port1[e] : 0;
        pB[tid] = v ? port2[e] : 0;
        mk[tid] = v ? nfict[e] : 0.f;
    }
    __syncthreads();
    gatherX(X, coords, efeat, pA, pB, ebase, tid);
    __syncthreads();

    #pragma unroll 1
    for (int mlp = 0; mlp < 2; ++mlp) {
        if (mlp) __syncthreads();       // all waves done reading H (mlp0 L3)
        const u16* wh = Whi + mlp * SZ_MLP;
        const float* bb1 = mlp ? b1b : b1a;
        const float* bb2 = mlp ? b2b : b2a;
        const float* bb3 = mlp ? b3b : b3a;
        const int*   pp  = mlp ? pB  : pA;

        f32x4 acc[MT][4];
        layer_mm<KC1, KC1, 4, NT1>(X, wh, wave, lane, acc);             // 272->256
        epi_relu<4>(H, bb1, wave, lane, acc);                           // X intact
        __syncthreads();                                                // H1 ready
        layer_mm<KC2, KC2, 4, NT2>(H, wh + SZ1, wave, lane, acc);       // 256->256
        __syncthreads();                                                // H1 reads done
        epi_relu<4>(H, bb2, wave, lane, acc);                           // H2 over H1
        __syncthreads();                                                // H2 ready
        f32x4 acc3[MT][2];
        layer_mm<KC2, KC2, 2, NT3>(H, wh + SZ1 + SZ2, wave, lane, acc3); // 256->128

        // scatter: bias, mask, atomic add into out (fire-and-forget)
        int quad = lane >> 4, ln = lane & 15;
        #pragma unroll
        for (int t = 0; t < 2; ++t) {
            int n = (wave * 2 + t) * 16 + ln;
            float b = bb3[n];
            #pragma unroll
            for (int mt = 0; mt < MT; ++mt)
                #pragma unroll
                for (int r = 0; r < 4; ++r) {
                    int m = mt * 16 + quad * 4 + r;
                    float v = (acc3[mt][t][r] + b) * mk[m];
                    unsafeAtomicAdd(out + (size_t)pp[m] * OUT_DIM + n, v);
                }
        }
    }
}

__global__ void tanh_kernel(float* __restrict__ out, int n) {
    int i = (blockIdx.x * 256 + threadIdx.x) * 4;
    if (i + 3 < n) {
        float4 v = *(float4*)(out + i);
        v.x = tanhf(v.x); v.y = tanhf(v.y); v.z = tanhf(v.z); v.w = tanhf(v.w);
        *(float4*)(out + i) = v;
    } else {
        for (int k = i; k < n; ++k) out[k] = tanhf(out[k]);
    }
}

extern "C" void kernel_launch(void* const* d_in, const int* in_sizes, int n_in,
                              void* d_out, int out_size, void* d_ws, size_t ws_size,
                              hipStream_t stream) {
    const float* coords = (const float*)d_in[0];
    const float* efeat  = (const float*)d_in[1];
    const float* nfict  = (const float*)d_in[2];
    const int*   p1     = (const int*)d_in[3];
    const int*   p2     = (const int*)d_in[4];
    const float* W1a = (const float*)d_in[5];  const float* b1a = (const float*)d_in[6];
    const float* W2a = (const float*)d_in[7];  const float* b2a = (const float*)d_in[8];
    const float* W3a = (const float*)d_in[9];  const float* b3a = (const float*)d_in[10];
    const float* W1b = (const float*)d_in[11]; const float* b1b = (const float*)d_in[12];
    const float* W2b = (const float*)d_in[13]; const float* b2b = (const float*)d_in[14];
    const float* W3b = (const float*)d_in[15]; const float* b3b = (const float*)d_in[16];
    float* out = (float*)d_out;
    u16* Whi = (u16*)d_ws;                 // needs SZ_ALL*2 = 688,128 B of ws

    hipMemsetAsync(d_out, 0, (size_t)out_size * sizeof(float), stream);
    prep_weights<<<SZ_ALL / 256, 256, 0, stream>>>(W1a, W2a, W3a, W1b, W2b, W3b, Whi);
    int nblk = (N_EDGES_C + EPB - 1) / EPB;
    fused_mlp<<<nblk, 256, 0, stream>>>(coords, efeat, nfict, p1, p2,
                                        b1a, b2a, b3a, b1b, b2b, b3b, Whi, out);
    int n4 = (out_size + 3) / 4;
    tanh_kernel<<<(n4 + 255) / 256, 256, 0, stream>>>(out, out_size);
}